// Round 9
// baseline (1075.510 us; speedup 1.0000x reference)
//
#include <hip/hip_runtime.h>
#include <hip/hip_bf16.h>

typedef unsigned short u16;
typedef __attribute__((ext_vector_type(8))) short short8;   // 8 bf16 (4 VGPRs)
typedef __attribute__((ext_vector_type(4))) float f32x4;    // MFMA accumulator

#define DEV static __device__ __forceinline__

DEV u16 f2bf(float x){
  union { __hip_bfloat16 b; u16 u; } c;
  c.b = __float2bfloat16(x);   // RNE
  return c.u;
}

DEV void gload16(const void* g, void* lds){
  __builtin_amdgcn_global_load_lds((const __attribute__((address_space(1))) void*)g,
                                   (__attribute__((address_space(3))) void*)lds, 16, 0, 0);
}

// ---------------------------------------------------------------------------
// Weight convert + transpose: src fp32 [K=256][N] -> dst bf16 [N][256]
// 64x64 tiles, 512 threads.
// ---------------------------------------------------------------------------
__global__ __launch_bounds__(512)
void wconv_kernel(const float* __restrict__ Wq, const float* __restrict__ Wk,
                  const float* __restrict__ Wv, const float* __restrict__ Wo,
                  const float* __restrict__ W1, const float* __restrict__ W2,
                  const float* __restrict__ Wh,
                  u16* __restrict__ WqkvT, u16* __restrict__ WoT,
                  u16* __restrict__ W1T, u16* __restrict__ W2T, u16* __restrict__ WhT)
{
  __shared__ float tile[64][65];
  const int j = blockIdx.y;
  int N = 256;
  const float* src; u16* dst;
  if (j < 48){
    const int li = j / 6, t = j % 6;
    switch(t){
      case 0:  src = Wq + li*65536; dst = WqkvT + li*196608;          break;
      case 1:  src = Wk + li*65536; dst = WqkvT + li*196608 + 65536;  break;
      case 2:  src = Wv + li*65536; dst = WqkvT + li*196608 + 131072; break;
      case 3:  src = Wo + li*65536; dst = WoT  + li*65536;            break;
      case 4:  src = W1 + li*65536; dst = W1T  + li*65536;            break;
      default: src = W2 + li*65536; dst = W2T  + li*65536;            break;
    }
  } else { N = 512; src = Wh; dst = WhT; }
  const int tilesPerRow = N >> 6;
  if ((int)blockIdx.x >= tilesPerRow * 4) return;
  const int tx = blockIdx.x % tilesPerRow, ty = blockIdx.x / tilesPerRow;
  const int tid = threadIdx.x;
  #pragma unroll
  for (int i=0;i<2;++i){
    const int e = tid + i*512;
    const int r = e >> 4, cq = (e & 15)*4;
    float4 v = *(const float4*)(src + (size_t)(ty*64 + r)*N + tx*64 + cq);
    tile[r][cq+0]=v.x; tile[r][cq+1]=v.y; tile[r][cq+2]=v.z; tile[r][cq+3]=v.w;
  }
  __syncthreads();
  #pragma unroll
  for (int i=0;i<2;++i){
    const int e = tid + i*512;
    const int orow = e >> 4, tq = (e & 15)*4;
    ushort4 o;
    o.x = f2bf(tile[tq+0][orow]); o.y = f2bf(tile[tq+1][orow]);
    o.z = f2bf(tile[tq+2][orow]); o.w = f2bf(tile[tq+3][orow]);
    *(ushort4*)(dst + (size_t)(tx*64 + orow)*256 + ty*64 + tq) = o;
  }
}

// ---------------------------------------------------------------------------
// Embedding + positional encoding + LN1(layer0): one wave per row.
// ---------------------------------------------------------------------------
__global__ __launch_bounds__(256)
void embed_ln_kernel(const int* __restrict__ idx, const float* __restrict__ emb,
                     const float* __restrict__ g, const float* __restrict__ be,
                     float* __restrict__ x, u16* __restrict__ hb)
{
  const int tid = threadIdx.x;
  const int w = tid >> 6, l = tid & 63;
  const int row = blockIdx.x*4 + w;
  const int t = row & 255;
  const int v = idx[row];
  const int c4 = l*4;
  float4 e = *(const float4*)(emb + (size_t)v*256 + c4);
  float r[4];
  const float ef[4] = {e.x, e.y, e.z, e.w};
  #pragma unroll
  for (int i=0;i<4;++i){
    const int c = c4 + i;
    const float div = expf((float)(c & ~1) * (-9.210340371976184f/256.f));
    const float ang = (float)t * div;
    r[i] = ((c & 1) ? cosf(ang) : sinf(ang)) + ef[i];
  }
  *(float4*)(x + (size_t)row*256 + c4) = (float4){r[0],r[1],r[2],r[3]};
  float s = r[0]+r[1]+r[2]+r[3];
  float q = r[0]*r[0]+r[1]*r[1]+r[2]*r[2]+r[3]*r[3];
  #pragma unroll
  for (int m=32; m; m>>=1){ s += __shfl_xor(s,m); q += __shfl_xor(q,m); }
  const float mu = s * (1.f/256.f);
  const float var = q * (1.f/256.f) - mu*mu;
  const float rstd = rsqrtf(var + 1e-5f);
  const float4 gv = *(const float4*)(g + c4);
  const float4 bv = *(const float4*)(be + c4);
  ushort4 o;
  o.x = f2bf((r[0]-mu)*rstd*gv.x + bv.x);
  o.y = f2bf((r[1]-mu)*rstd*gv.y + bv.y);
  o.z = f2bf((r[2]-mu)*rstd*gv.z + bv.z);
  o.w = f2bf((r[3]-mu)*rstd*gv.w + bv.w);
  *(ushort4*)(hb + (size_t)row*256 + c4) = o;
}

// ---------------------------------------------------------------------------
// Plain GEMM, 2-phase dbuf staging. C[M][N] = A[M][256] @ W^T[N][256].
// ---------------------------------------------------------------------------
template<bool OBF, bool RELU_, bool BIAS_>
__global__ __launch_bounds__(256)
void gemm_kernel(const u16* __restrict__ A, const u16* __restrict__ W,
                 const float* __restrict__ bias, void* __restrict__ Cv, int ldC)
{
  __shared__ __align__(16) u16 Al[2][4096];
  __shared__ __align__(16) u16 Bl[2][4096];
  const int tid = threadIdx.x;
  const int w = tid >> 6, l = tid & 63;
  const int lr = l & 15, lg = l >> 4;
  const int m0 = blockIdx.x * 128, n0 = blockIdx.y * 128;
  const int wm = w >> 1, wn = w & 1;
  const int rowc = l >> 2;
  const int pswz = (l & 3) ^ ((l >> 3) & 3);

  f32x4 acc[4][4];
  #pragma unroll
  for (int i=0;i<4;++i)
    #pragma unroll
    for (int jn=0;jn<4;++jn) acc[i][jn] = (f32x4){0.f,0.f,0.f,0.f};

  #pragma unroll
  for (int cc=0; cc<2; ++cc){
    const int c = w + cc*4;
    gload16(A + (size_t)(m0 + 16*c + rowc)*256 + pswz*8, &Al[0][c*512]);
    gload16(W + (size_t)(n0 + 16*c + rowc)*256 + pswz*8, &Bl[0][c*512]);
  }
  __syncthreads();

  for (int kt=0; kt<8; ++kt){
    if (kt < 7){
      const int kofs = (kt+1) * 32, nb = (kt+1) & 1;
      #pragma unroll
      for (int cc=0; cc<2; ++cc){
        const int c = w + cc*4;
        gload16(A + (size_t)(m0 + 16*c + rowc)*256 + kofs + pswz*8, &Al[nb][c*512]);
        gload16(W + (size_t)(n0 + 16*c + rowc)*256 + kofs + pswz*8, &Bl[nb][c*512]);
      }
    }
    const int buf = kt & 1;
    short8 af[4], bf[4];
    #pragma unroll
    for (int mt=0; mt<4; ++mt){
      const int row = wm*64 + mt*16 + lr;
      const int kb = (lg*16) ^ ((((row>>1)&3))<<4);
      af[mt] = *(const short8*)((const char*)Al[buf] + row*64 + kb);
    }
    #pragma unroll
    for (int nt=0; nt<4; ++nt){
      const int row = wn*64 + nt*16 + lr;
      const int kb = (lg*16) ^ ((((row>>1)&3))<<4);
      bf[nt] = *(const short8*)((const char*)Bl[buf] + row*64 + kb);
    }
    #pragma unroll
    for (int mt=0; mt<4; ++mt)
      #pragma unroll
      for (int nt=0; nt<4; ++nt)
        acc[mt][nt] = __builtin_amdgcn_mfma_f32_16x16x32_bf16(af[mt], bf[nt], acc[mt][nt], 0,0,0);
    __syncthreads();
  }

  #pragma unroll
  for (int nt=0; nt<4; ++nt){
    const int col = n0 + wn*64 + nt*16 + lr;
    const float bv = BIAS_ ? bias[col] : 0.f;
    #pragma unroll
    for (int mt=0; mt<4; ++mt){
      f32x4 v = acc[mt][nt];
      #pragma unroll
      for (int r=0;r<4;++r){
        const int row = m0 + wm*64 + mt*16 + lg*4 + r;
        float val = v[r] + bv;
        if (RELU_) val = fmaxf(val, 0.f);
        if (OBF) ((u16*)Cv)[(size_t)row*ldC + col] = f2bf(val);
        else     ((float*)Cv)[(size_t)row*ldC + col] = val;
      }
    }
  }
}

// ---------------------------------------------------------------------------
// GEMM + residual + LayerNorm epilogue. Block = 64 full rows (grid 512).
// ---------------------------------------------------------------------------
__global__ __launch_bounds__(256, 2)
void gemm_res_ln_kernel(const u16* __restrict__ A, const u16* __restrict__ W,
                        const float* __restrict__ bias,
                        const float* __restrict__ g, const float* __restrict__ be,
                        float* __restrict__ x, u16* __restrict__ hb)
{
  __shared__ __align__(16) u16 Al[2][2048];   // [64][32]
  __shared__ __align__(16) u16 Bl[2][8192];   // [256][32]
  __shared__ float sS[64][2], sQ[64][2];
  const int tid = threadIdx.x;
  const int w = tid >> 6, l = tid & 63;
  const int lr = l & 15, lg = l >> 4;
  const int m0 = blockIdx.x * 64;
  const int wm = w >> 1, wn = w & 1;
  const int rowc = l >> 2;
  const int pswz = (l & 3) ^ ((l >> 3) & 3);

  f32x4 acc[2][2][4];
  #pragma unroll
  for (int p=0;p<2;++p)
    #pragma unroll
    for (int i=0;i<2;++i)
      #pragma unroll
      for (int jn=0;jn<4;++jn) acc[p][i][jn] = (f32x4){0.f,0.f,0.f,0.f};

  gload16(A + (size_t)(m0 + 16*w + rowc)*256 + pswz*8, &Al[0][w*512]);
  #pragma unroll
  for (int cc=0; cc<4; ++cc){
    const int c = w + cc*4;
    gload16(W + (size_t)(16*c + rowc)*256 + pswz*8, &Bl[0][c*512]);
  }
  __syncthreads();

  for (int kt=0; kt<8; ++kt){
    if (kt < 7){
      const int kofs = (kt+1)*32, nb = (kt+1)&1;
      gload16(A + (size_t)(m0 + 16*w + rowc)*256 + kofs + pswz*8, &Al[nb][w*512]);
      #pragma unroll
      for (int cc=0; cc<4; ++cc){
        const int c = w + cc*4;
        gload16(W + (size_t)(16*c + rowc)*256 + kofs + pswz*8, &Bl[nb][c*512]);
      }
    }
    const int buf = kt & 1;
    short8 af[2], bf[2][4];
    #pragma unroll
    for (int mt=0; mt<2; ++mt){
      const int row = wm*32 + mt*16 + lr;
      const int kb = (lg*16) ^ ((((row>>1)&3))<<4);
      af[mt] = *(const short8*)((const char*)Al[buf] + row*64 + kb);
    }
    #pragma unroll
    for (int p=0; p<2; ++p)
      #pragma unroll
      for (int nt=0; nt<4; ++nt){
        const int brow = p*128 + wn*64 + nt*16 + lr;
        const int kb = (lg*16) ^ ((((brow>>1)&3))<<4);
        bf[p][nt] = *(const short8*)((const char*)Bl[buf] + brow*64 + kb);
      }
    #pragma unroll
    for (int p=0; p<2; ++p)
      #pragma unroll
      for (int mt=0; mt<2; ++mt)
        #pragma unroll
        for (int nt=0; nt<4; ++nt)
          acc[p][mt][nt] = __builtin_amdgcn_mfma_f32_16x16x32_bf16(af[mt], bf[p][nt], acc[p][mt][nt], 0,0,0);
    __syncthreads();
  }

  float bcol[2][4], gcol[2][4], becol[2][4];
  #pragma unroll
  for (int p=0;p<2;++p)
    #pragma unroll
    for (int nt=0;nt<4;++nt){
      const int col = p*128 + wn*64 + nt*16 + lr;
      bcol[p][nt] = bias[col]; gcol[p][nt] = g[col]; becol[p][nt] = be[col];
    }
  float s8[2][4], q8[2][4];
  #pragma unroll
  for (int mt=0;mt<2;++mt)
    #pragma unroll
    for (int rr=0;rr<4;++rr){ s8[mt][rr]=0.f; q8[mt][rr]=0.f; }

  #pragma unroll
  for (int p=0;p<2;++p)
    #pragma unroll
    for (int mt=0;mt<2;++mt)
      #pragma unroll
      for (int nt=0;nt<4;++nt)
        #pragma unroll
        for (int rr=0;rr<4;++rr){
          const int row = m0 + wm*32 + mt*16 + lg*4 + rr;
          const int col = p*128 + wn*64 + nt*16 + lr;
          float val = acc[p][mt][nt][rr] + bcol[p][nt] + x[(size_t)row*256 + col];
          x[(size_t)row*256 + col] = val;
          acc[p][mt][nt][rr] = val;
          s8[mt][rr] += val; q8[mt][rr] += val*val;
        }
  #pragma unroll
  for (int mt=0;mt<2;++mt)
    #pragma unroll
    for (int rr=0;rr<4;++rr){
      #pragma unroll
      for (int m=1; m<16; m<<=1){
        s8[mt][rr] += __shfl_xor(s8[mt][rr], m);
        q8[mt][rr] += __shfl_xor(q8[mt][rr], m);
      }
      if (lr == 0){
        const int lrow = wm*32 + mt*16 + lg*4 + rr;
        sS[lrow][wn] = s8[mt][rr]; sQ[lrow][wn] = q8[mt][rr];
      }
    }
  __syncthreads();

  #pragma unroll
  for (int mt=0;mt<2;++mt)
    #pragma unroll
    for (int rr=0;rr<4;++rr){
      const int lrow = wm*32 + mt*16 + lg*4 + rr;
      const float mu = (sS[lrow][0] + sS[lrow][1]) * (1.f/256.f);
      const float var = (sQ[lrow][0] + sQ[lrow][1]) * (1.f/256.f) - mu*mu;
      const float rstd = rsqrtf(var + 1e-5f);
      #pragma unroll
      for (int p=0;p<2;++p)
        #pragma unroll
        for (int nt=0;nt<4;++nt){
          const int col = p*128 + wn*64 + nt*16 + lr;
          const float out = (acc[p][mt][nt][rr] - mu)*rstd*gcol[p][nt] + becol[p][nt];
          hb[(size_t)(m0+lrow)*256 + col] = f2bf(out);
        }
    }
}

// ---------------------------------------------------------------------------
// FUSED QKV-projection + causal attention, one block per (b,h).
// 8 waves x 512 threads. Phase A: waves 0-3 project K (A=Wk d-rows, B=hb
// t-rows -> C[d][t], packed ushort4 into swizzled sK[t][d]); waves 4-7
// project V (A=hb, B=Wv -> C[t][d], packed into swizzled sV[d][t]).
// Per q-tile: project Q (A=Wq, B=hb q-rows) through wave-private sPw, then
// swapped QK^T, in-lane softmax, PV. A/B fragments read from global
// (weights L2-resident, hb L3-resident). LDS 80 KiB -> 2 blocks/CU.
// ---------------------------------------------------------------------------
__global__ __launch_bounds__(512, 4)
void fused_qkv_attn_kernel(const u16* __restrict__ hb, const u16* __restrict__ Wqkv,
                           u16* __restrict__ att)
{
  __shared__ __align__(16) u16 sK[16384];   // [256 t][64 d] swz (row 128B)
  __shared__ __align__(16) u16 sV[16384];   // [64 d][256 t] swz (row 512B)
  __shared__ __align__(16) u16 sP[8192];    // 8 waves x 2 KiB (Q tile / P tile)
  const int bh = blockIdx.x;
  const int b = bh >> 2, h = bh & 3;
  const int tid = threadIdx.x;
  const int w = tid >> 6, l = tid & 63, lr = l & 15, lg = l >> 4;
  const u16* hbb = hb + (size_t)(b*256)*256;
  const u16* Wq_ = Wqkv + (size_t)(h*64)*256;
  const u16* Wk_ = Wqkv + 65536 + (size_t)(h*64)*256;
  const u16* Wv_ = Wqkv + 131072 + (size_t)(h*64)*256;

  // ---- Phase A: project K (waves 0-3) and V (waves 4-7) ----
  {
    f32x4 pacc[4][4];
    #pragma unroll
    for (int i=0;i<4;++i)
      #pragma unroll
      for (int jn=0;jn<4;++jn) pacc[i][jn] = (f32x4){0.f,0.f,0.f,0.f};
    if (w < 4){
      const int t0 = w*64;
      for (int kt=0; kt<8; ++kt){
        short8 af[4], bf[4];
        #pragma unroll
        for (int mt=0; mt<4; ++mt)
          af[mt] = *(const short8*)(Wk_ + (size_t)(mt*16+lr)*256 + kt*32 + lg*8);
        #pragma unroll
        for (int nt=0; nt<4; ++nt)
          bf[nt] = *(const short8*)(hbb + (size_t)(t0+nt*16+lr)*256 + kt*32 + lg*8);
        #pragma unroll
        for (int mt=0; mt<4; ++mt)
          #pragma unroll
          for (int nt=0; nt<4; ++nt)
            pacc[mt][nt] = __builtin_amdgcn_mfma_f32_16x16x32_bf16(af[mt], bf[nt], pacc[mt][nt], 0,0,0);
      }
      // C[d][t]: d = mt*16+lg*4+r, t = t0+nt*16+lr -> sK[t][d-quad] packed
      #pragma unroll
      for (int mt=0; mt<4; ++mt)
        #pragma unroll
        for (int nt=0; nt<4; ++nt){
          const int t = t0 + nt*16 + lr;
          ushort4 o;
          o.x = f2bf(pacc[mt][nt][0]); o.y = f2bf(pacc[mt][nt][1]);
          o.z = f2bf(pacc[mt][nt][2]); o.w = f2bf(pacc[mt][nt][3]);
          *(ushort4*)((char*)sK + t*128 + ((mt*32 + lg*8) ^ ((t&7)<<4))) = o;
        }
    } else {
      const int t0 = (w-4)*64;
      for (int kt=0; kt<8; ++kt){
        short8 af[4], bf[4];
        #pragma unroll
        for (int mt=0; mt<4; ++mt)
          af[mt] = *(const short8*)(hbb + (size_t)(t0+mt*16+lr)*256 + kt*32 + lg*8);
        #pragma unroll
        for (int nt=0; nt<4; ++nt)
          bf[nt] = *(const short8*)(Wv_ + (size_t)(nt*16+lr)*256 + kt*32 + lg*8);
        #pragma unroll
        for (int mt=0; mt<4; ++mt)
          #pragma unroll
          for (int nt=0; nt<4; ++nt)
            pacc[mt][nt] = __builtin_amdgcn_mfma_f32_16x16x32_bf16(af[mt], bf[nt], pacc[mt][nt], 0,0,0);
      }
      // C[t][d]: t = t0+mt*16+lg*4+r, d = nt*16+lr -> sV[d][t-quad] packed
      #pragma unroll
      for (int mt=0; mt<4; ++mt)
        #pragma unroll
        for (int nt=0; nt<4; ++nt){
          const int d = nt*16 + lr;
          ushort4 o;
          o.x = f2bf(pacc[mt][nt][0]); o.y = f2bf(pacc[mt][nt][1]);
          o.z = f2bf(pacc[mt][nt][2]); o.w = f2bf(pacc[mt][nt][3]);
          *(ushort4*)((char*)sV + d*512 + (((t0 + mt*16 + lg*4)*2) ^ ((d&31)<<4))) = o;
        }
    }
  }
  __syncthreads();

  char* sPw = (char*)sP + w*2048;     // wave-private 2 KiB (Q then P, serially)
  const int swzq = (lr & 7) << 4;
  u16* ab = att + (size_t)(b*256)*256 + h*64;
  const float c1 = 0.09016844005556021f;   // (1/16) * log2(e)

  #pragma unroll
  for (int ph=0; ph<2; ++ph){
    const int rt = ph ? (15 - w) : w;      // q-row-tile (16 rows); 17 tiles/wave

    // ---- Q projection for this tile: C[d][q], write sPw[q][d] packed ----
    {
      f32x4 qacc[4];
      #pragma unroll
      for (int mt=0; mt<4; ++mt) qacc[mt] = (f32x4){0.f,0.f,0.f,0.f};
      for (int kt=0; kt<8; ++kt){
        const short8 bq = *(const short8*)(hbb + (size_t)(rt*16+lr)*256 + kt*32 + lg*8);
        #pragma unroll
        for (int mt=0; mt<4; ++mt){
          const short8 aq = *(const short8*)(Wq_ + (size_t)(mt*16+lr)*256 + kt*32 + lg*8);
          qacc[mt] = __builtin_amdgcn_mfma_f32_16x16x32_bf16(aq, bq, qacc[mt], 0,0,0);
        }
      }
      // d = mt*16+lg*4+r, q = lr -> sPw byte q*128 + ((d*2) ^ ((q&7)<<4))
      #pragma unroll
      for (int mt=0; mt<4; ++mt){
        ushort4 o;
        o.x = f2bf(qacc[mt][0]); o.y = f2bf(qacc[mt][1]);
        o.z = f2bf(qacc[mt][2]); o.w = f2bf(qacc[mt][3]);
        *(ushort4*)(sPw + lr*128 + ((mt*32 + lg*8) ^ swzq)) = o;
      }
    }
    const short8 qf0 = *(const short8*)(sPw + lr*128 + ((lg*16) ^ swzq));
    const short8 qf1 = *(const short8*)(sPw + lr*128 + ((64 + lg*16) ^ swzq));

    // ---- QK^T swapped: acc[nt][r] = S[q = rt*16+lr][t = nt*16+lg*4+r] ----
    f32x4 acc[16];
    #pragma unroll
    for (int nt=0; nt<16; ++nt) acc[nt] = (f32x4){0.f,0.f,0.f,0.f};
    #pragma unroll
    for (int nt=0; nt<16; ++nt){
      if (nt <= rt){
        const int row = nt*16 + lr;
        const int swz = (row & 7) << 4;
        short8 k0 = *(const short8*)((const char*)sK + row*128 + ((lg*16) ^ swz));
        short8 k1 = *(const short8*)((const char*)sK + row*128 + ((64 + lg*16) ^ swz));
        acc[nt] = __builtin_amdgcn_mfma_f32_16x16x32_bf16(k0, qf0, acc[nt], 0,0,0);
        acc[nt] = __builtin_amdgcn_mfma_f32_16x16x32_bf16(k1, qf1, acc[nt], 0,0,0);
      }
    }
    // diagonal-tile causal mask
    #pragma unroll
    for (int nt=0; nt<16; ++nt){
      if (nt == rt){
        #pragma unroll
        for (int r=0;r<4;++r)
          acc[nt][r] = (lg*4 + r > lr) ? -3.0e38f : acc[nt][r];
      }
    }

    // ---- per-lane softmax over t ----
    float m_ = -3.0e38f;
    #pragma unroll
    for (int nt=0; nt<16; ++nt){
      if (nt <= rt){
        float t01 = fmaxf(acc[nt][0], acc[nt][1]);
        float t23 = fmaxf(acc[nt][2], acc[nt][3]);
        m_ = fmaxf(m_, fmaxf(t01, t23));
      }
    }
    m_ = fmaxf(m_, __shfl_xor(m_, 16));
    m_ = fmaxf(m_, __shfl_xor(m_, 32));
    const float mm = m_ * c1;
    float s_ = 0.f;
    #pragma unroll
    for (int nt=0; nt<16; ++nt){
      if (nt <= rt){
        #pragma unroll
        for (int r=0;r<4;++r){
          const float p = exp2f(fmaf(acc[nt][r], c1, -mm));
          acc[nt][r] = p;
          s_ += p;
        }
      }
    }
    s_ += __shfl_xor(s_, 16);
    s_ += __shfl_xor(s_, 32);
    const float inv = 1.f / s_;

    // ---- PV over 64-t chunks through wave-private LDS ----
    f32x4 oacc[4];
    #pragma unroll
    for (int nt=0; nt<4; ++nt) oacc[nt] = (f32x4){0.f,0.f,0.f,0.f};
    #pragma unroll
    for (int c=0; c<4; ++c){
      if (c <= (rt >> 2)){
        #pragma unroll
        for (int e=0; e<4; ++e){
          const int nt = 4*c + e;
          ushort4 pk;
          #pragma unroll
          for (int r=0;r<4;++r){
            const float val = (nt <= rt) ? acc[nt][r] * inv : 0.f;
            ((u16*)&pk)[r] = f2bf(val);
          }
          *(ushort4*)(sPw + lr*128 + ((e*32 + lg*8) ^ swzq)) = pk;
        }
        #pragma unroll
        for (int kc=0; kc<2; ++kc){
          const int tc = 2*c + kc;
          if (tc <= (rt >> 1)){
            const short8 ap = *(const short8*)(sPw + lr*128 + ((kc*64 + lg*16) ^ swzq));
            #pragma unroll
            for (int nt=0; nt<4; ++nt){
              const int vrow = nt*16 + lr;
              const short8 bv = *(const short8*)((const char*)sV + vrow*512 +
                                   ((tc*64 + lg*16) ^ ((vrow&31)<<4)));
              oacc[nt] = __builtin_amdgcn_mfma_f32_16x16x32_bf16(ap, bv, oacc[nt], 0,0,0);
            }
          }
        }
      }
    }

    // ---- write O [16 q][64 hd] ----
    #pragma unroll
    for (int nt=0; nt<4; ++nt)
      #pragma unroll
      for (int r=0;r<4;++r){
        const int row = rt*16 + lg*4 + r;
        ab[(size_t)row*256 + nt*16 + lr] = f2bf(oacc[nt][r]);
      }
  }
}

// ---------------------------------------------------------------------------
extern "C" void kernel_launch(void* const* d_in, const int* in_sizes, int n_in,
                              void* d_out, int out_size, void* d_ws, size_t ws_size,
                              hipStream_t stream)
{
  (void)in_sizes; (void)n_in; (void)out_size; (void)ws_size;
  const int*   idx = (const int*)  d_in[0];
  const float* tok = (const float*)d_in[1];
  const float* Wq  = (const float*)d_in[2];
  const float* Wk  = (const float*)d_in[3];
  const float* Wv  = (const float*)d_in[4];
  const float* Wo  = (const float*)d_in[5];
  const float* bo  = (const float*)d_in[6];
  const float* W1  = (const float*)d_in[7];
  const float* b1  = (const float*)d_in[8];
  const float* W2  = (const float*)d_in[9];
  const float* b2  = (const float*)d_in[10];
  const float* g1  = (const float*)d_in[11];
  const float* be1 = (const float*)d_in[12];
  const float* g2  = (const float*)d_in[13];
  const float* be2 = (const float*)d_in[14];
  const float* gf  = (const float*)d_in[15];
  const float* bfi = (const float*)d_in[16];
  const float* Wh  = (const float*)d_in[17];
  const float* bh  = (const float*)d_in[18];

  char* ws = (char*)d_ws;
  float* x    = (float*)ws;  ws += (size_t)32768*256*4;   // residual stream f32
  u16*   hb   = (u16*)ws;    ws += (size_t)32768*256*2;   // LN output bf16
  u16*   mid  = (u16*)ws;    ws += (size_t)32768*256*2;   // FFN mid bf16
  u16*   att  = (u16*)ws;    ws += (size_t)32768*256*2;   // attn out bf16
  u16*   WqkvT= (u16*)ws;    ws += (size_t)8*768*256*2;
  u16*   WoT  = (u16*)ws;    ws += (size_t)8*256*256*2;
  u16*   W1T  = (u16*)ws;    ws += (size_t)8*256*256*2;
  u16*   W2T  = (u16*)ws;    ws += (size_t)8*256*256*2;
  u16*   WhT  = (u16*)ws;    ws += (size_t)512*256*2;

  wconv_kernel<<<dim3(32,49),512,0,stream>>>(Wq,Wk,Wv,Wo,W1,W2,Wh,WqkvT,WoT,W1T,W2T,WhT);
  embed_ln_kernel<<<8192,256,0,stream>>>(idx, tok, g1, be1, x, hb);
  for (int l=0; l<8; ++l){
    fused_qkv_attn_kernel<<<512,512,0,stream>>>(hb, WqkvT + (size_t)l*196608, att);
    gemm_res_ln_kernel<<<512,256,0,stream>>>(
        att, WoT + (size_t)l*65536, bo + l*256, g2 + l*256, be2 + l*256, x, hb);
    gemm_kernel<true,true,true><<<dim3(256,2),256,0,stream>>>(
        hb, W1T + (size_t)l*65536, b1 + l*256, mid, 256);
    const float* gn = (l < 7) ? (g1 + (l+1)*256) : gf;
    const float* bn = (l < 7) ? (be1 + (l+1)*256) : bfi;
    gemm_res_ln_kernel<<<512,256,0,stream>>>(
        mid, W2T + (size_t)l*65536, b2 + l*256, gn, bn, x, hb);
  }
  gemm_kernel<false,false,true><<<dim3(256,4),256,0,stream>>>(
      hb, WhT, bh, (float*)d_out, 512);
}

// Round 10
// 795.043 us; speedup vs baseline: 1.3528x; 1.3528x over previous
//
#include <hip/hip_runtime.h>
#include <hip/hip_bf16.h>

typedef unsigned short u16;
typedef __attribute__((ext_vector_type(8))) short short8;   // 8 bf16 (4 VGPRs)
typedef __attribute__((ext_vector_type(4))) float f32x4;    // MFMA accumulator

#define DEV static __device__ __forceinline__

DEV u16 f2bf(float x){
  union { __hip_bfloat16 b; u16 u; } c;
  c.b = __float2bfloat16(x);   // RNE
  return c.u;
}
DEV float bf2f(u16 u){
  union { float f; unsigned i; } c;
  c.i = ((unsigned)u) << 16;
  return c.f;
}

DEV void gload16(const void* g, void* lds){
  __builtin_amdgcn_global_load_lds((const __attribute__((address_space(1))) void*)g,
                                   (__attribute__((address_space(3))) void*)lds, 16, 0, 0);
}

// ---------------------------------------------------------------------------
// Weight convert + transpose: src fp32 [K=256][N] -> dst bf16 [N][256]
// 64x64 tiles, 512 threads.
// ---------------------------------------------------------------------------
__global__ __launch_bounds__(512)
void wconv_kernel(const float* __restrict__ Wq, const float* __restrict__ Wk,
                  const float* __restrict__ Wv, const float* __restrict__ Wo,
                  const float* __restrict__ W1, const float* __restrict__ W2,
                  const float* __restrict__ Wh,
                  u16* __restrict__ WqkvT, u16* __restrict__ WoT,
                  u16* __restrict__ W1T, u16* __restrict__ W2T, u16* __restrict__ WhT)
{
  __shared__ float tile[64][65];
  const int j = blockIdx.y;
  int N = 256;
  const float* src; u16* dst;
  if (j < 48){
    const int li = j / 6, t = j % 6;
    switch(t){
      case 0:  src = Wq + li*65536; dst = WqkvT + li*196608;          break;
      case 1:  src = Wk + li*65536; dst = WqkvT + li*196608 + 65536;  break;
      case 2:  src = Wv + li*65536; dst = WqkvT + li*196608 + 131072; break;
      case 3:  src = Wo + li*65536; dst = WoT  + li*65536;            break;
      case 4:  src = W1 + li*65536; dst = W1T  + li*65536;            break;
      default: src = W2 + li*65536; dst = W2T  + li*65536;            break;
    }
  } else { N = 512; src = Wh; dst = WhT; }
  const int tilesPerRow = N >> 6;
  if ((int)blockIdx.x >= tilesPerRow * 4) return;
  const int tx = blockIdx.x % tilesPerRow, ty = blockIdx.x / tilesPerRow;
  const int tid = threadIdx.x;
  #pragma unroll
  for (int i=0;i<2;++i){
    const int e = tid + i*512;
    const int r = e >> 4, cq = (e & 15)*4;
    float4 v = *(const float4*)(src + (size_t)(ty*64 + r)*N + tx*64 + cq);
    tile[r][cq+0]=v.x; tile[r][cq+1]=v.y; tile[r][cq+2]=v.z; tile[r][cq+3]=v.w;
  }
  __syncthreads();
  #pragma unroll
  for (int i=0;i<2;++i){
    const int e = tid + i*512;
    const int orow = e >> 4, tq = (e & 15)*4;
    ushort4 o;
    o.x = f2bf(tile[tq+0][orow]); o.y = f2bf(tile[tq+1][orow]);
    o.z = f2bf(tile[tq+2][orow]); o.w = f2bf(tile[tq+3][orow]);
    *(ushort4*)(dst + (size_t)(tx*64 + orow)*256 + ty*64 + tq) = o;
  }
}

// ---------------------------------------------------------------------------
// Embedding + positional encoding + LN1(layer0): one wave per row.
// Writes x (bf16 residual) and hb (bf16 LN output).
// ---------------------------------------------------------------------------
__global__ __launch_bounds__(256)
void embed_ln_kernel(const int* __restrict__ idx, const float* __restrict__ emb,
                     const float* __restrict__ g, const float* __restrict__ be,
                     u16* __restrict__ x, u16* __restrict__ hb)
{
  const int tid = threadIdx.x;
  const int w = tid >> 6, l = tid & 63;
  const int row = blockIdx.x*4 + w;
  const int t = row & 255;
  const int v = idx[row];
  const int c4 = l*4;
  float4 e = *(const float4*)(emb + (size_t)v*256 + c4);
  float r[4];
  const float ef[4] = {e.x, e.y, e.z, e.w};
  #pragma unroll
  for (int i=0;i<4;++i){
    const int c = c4 + i;
    const float div = expf((float)(c & ~1) * (-9.210340371976184f/256.f));
    const float ang = (float)t * div;
    r[i] = ((c & 1) ? cosf(ang) : sinf(ang)) + ef[i];
  }
  ushort4 xo;
  xo.x = f2bf(r[0]); xo.y = f2bf(r[1]); xo.z = f2bf(r[2]); xo.w = f2bf(r[3]);
  *(ushort4*)(x + (size_t)row*256 + c4) = xo;
  float s = r[0]+r[1]+r[2]+r[3];
  float q = r[0]*r[0]+r[1]*r[1]+r[2]*r[2]+r[3]*r[3];
  #pragma unroll
  for (int m=32; m; m>>=1){ s += __shfl_xor(s,m); q += __shfl_xor(q,m); }
  const float mu = s * (1.f/256.f);
  const float var = q * (1.f/256.f) - mu*mu;
  const float rstd = rsqrtf(var + 1e-5f);
  const float4 gv = *(const float4*)(g + c4);
  const float4 bv = *(const float4*)(be + c4);
  ushort4 o;
  o.x = f2bf((r[0]-mu)*rstd*gv.x + bv.x);
  o.y = f2bf((r[1]-mu)*rstd*gv.y + bv.y);
  o.z = f2bf((r[2]-mu)*rstd*gv.z + bv.z);
  o.w = f2bf((r[3]-mu)*rstd*gv.w + bv.w);
  *(ushort4*)(hb + (size_t)row*256 + c4) = o;
}

// ---------------------------------------------------------------------------
// Plain GEMM, 2-phase dbuf staging. C[M][N] = A[M][256] @ W^T[N][256].
// 128x128 tile, 4 waves, LDS 32 KB.
// ---------------------------------------------------------------------------
template<bool OBF, bool RELU_, bool BIAS_>
__global__ __launch_bounds__(256)
void gemm_kernel(const u16* __restrict__ A, const u16* __restrict__ W,
                 const float* __restrict__ bias, void* __restrict__ Cv, int ldC)
{
  __shared__ __align__(16) u16 Al[2][4096];
  __shared__ __align__(16) u16 Bl[2][4096];
  const int tid = threadIdx.x;
  const int w = tid >> 6, l = tid & 63;
  const int lr = l & 15, lg = l >> 4;
  const int m0 = blockIdx.x * 128, n0 = blockIdx.y * 128;
  const int wm = w >> 1, wn = w & 1;
  const int rowc = l >> 2;
  const int pswz = (l & 3) ^ ((l >> 3) & 3);

  f32x4 acc[4][4];
  #pragma unroll
  for (int i=0;i<4;++i)
    #pragma unroll
    for (int jn=0;jn<4;++jn) acc[i][jn] = (f32x4){0.f,0.f,0.f,0.f};

  #pragma unroll
  for (int cc=0; cc<2; ++cc){
    const int c = w + cc*4;
    gload16(A + (size_t)(m0 + 16*c + rowc)*256 + pswz*8, &Al[0][c*512]);
    gload16(W + (size_t)(n0 + 16*c + rowc)*256 + pswz*8, &Bl[0][c*512]);
  }
  __syncthreads();

  for (int kt=0; kt<8; ++kt){
    if (kt < 7){
      const int kofs = (kt+1) * 32, nb = (kt+1) & 1;
      #pragma unroll
      for (int cc=0; cc<2; ++cc){
        const int c = w + cc*4;
        gload16(A + (size_t)(m0 + 16*c + rowc)*256 + kofs + pswz*8, &Al[nb][c*512]);
        gload16(W + (size_t)(n0 + 16*c + rowc)*256 + kofs + pswz*8, &Bl[nb][c*512]);
      }
    }
    const int buf = kt & 1;
    short8 af[4], bf[4];
    #pragma unroll
    for (int mt=0; mt<4; ++mt){
      const int row = wm*64 + mt*16 + lr;
      const int kb = (lg*16) ^ ((((row>>1)&3))<<4);
      af[mt] = *(const short8*)((const char*)Al[buf] + row*64 + kb);
    }
    #pragma unroll
    for (int nt=0; nt<4; ++nt){
      const int row = wn*64 + nt*16 + lr;
      const int kb = (lg*16) ^ ((((row>>1)&3))<<4);
      bf[nt] = *(const short8*)((const char*)Bl[buf] + row*64 + kb);
    }
    #pragma unroll
    for (int mt=0; mt<4; ++mt)
      #pragma unroll
      for (int nt=0; nt<4; ++nt)
        acc[mt][nt] = __builtin_amdgcn_mfma_f32_16x16x32_bf16(af[mt], bf[nt], acc[mt][nt], 0,0,0);
    __syncthreads();
  }

  #pragma unroll
  for (int nt=0; nt<4; ++nt){
    const int col = n0 + wn*64 + nt*16 + lr;
    const float bv = BIAS_ ? bias[col] : 0.f;
    #pragma unroll
    for (int mt=0; mt<4; ++mt){
      f32x4 v = acc[mt][nt];
      #pragma unroll
      for (int r=0;r<4;++r){
        const int row = m0 + wm*64 + mt*16 + lg*4 + r;
        float val = v[r] + bv;
        if (RELU_) val = fmaxf(val, 0.f);
        if (OBF) ((u16*)Cv)[(size_t)row*ldC + col] = f2bf(val);
        else     ((float*)Cv)[(size_t)row*ldC + col] = val;
      }
    }
  }
}

// ---------------------------------------------------------------------------
// GEMM + residual + LayerNorm epilogue. Block = 64 full rows (grid 512).
// C = A@W + bias + x  -> written back to x (bf16), then LN over the complete
// row (stats via shfl + small LDS cross-wave reduce) -> hb (bf16).
// Residual stream is bf16 (halves the dominant HBM traffic); adds in f32.
// ---------------------------------------------------------------------------
__global__ __launch_bounds__(256, 2)
void gemm_res_ln_kernel(const u16* __restrict__ A, const u16* __restrict__ W,
                        const float* __restrict__ bias,
                        const float* __restrict__ g, const float* __restrict__ be,
                        u16* __restrict__ x, u16* __restrict__ hb)
{
  __shared__ __align__(16) u16 Al[2][2048];   // [64][32]
  __shared__ __align__(16) u16 Bl[2][8192];   // [256][32]
  __shared__ float sS[64][2], sQ[64][2];
  const int tid = threadIdx.x;
  const int w = tid >> 6, l = tid & 63;
  const int lr = l & 15, lg = l >> 4;
  const int m0 = blockIdx.x * 64;
  const int wm = w >> 1, wn = w & 1;
  const int rowc = l >> 2;
  const int pswz = (l & 3) ^ ((l >> 3) & 3);

  f32x4 acc[2][2][4];
  #pragma unroll
  for (int p=0;p<2;++p)
    #pragma unroll
    for (int i=0;i<2;++i)
      #pragma unroll
      for (int jn=0;jn<4;++jn) acc[p][i][jn] = (f32x4){0.f,0.f,0.f,0.f};

  gload16(A + (size_t)(m0 + 16*w + rowc)*256 + pswz*8, &Al[0][w*512]);
  #pragma unroll
  for (int cc=0; cc<4; ++cc){
    const int c = w + cc*4;
    gload16(W + (size_t)(16*c + rowc)*256 + pswz*8, &Bl[0][c*512]);
  }
  __syncthreads();

  for (int kt=0; kt<8; ++kt){
    if (kt < 7){
      const int kofs = (kt+1)*32, nb = (kt+1)&1;
      gload16(A + (size_t)(m0 + 16*w + rowc)*256 + kofs + pswz*8, &Al[nb][w*512]);
      #pragma unroll
      for (int cc=0; cc<4; ++cc){
        const int c = w + cc*4;
        gload16(W + (size_t)(16*c + rowc)*256 + kofs + pswz*8, &Bl[nb][c*512]);
      }
    }
    const int buf = kt & 1;
    short8 af[2], bf[2][4];
    #pragma unroll
    for (int mt=0; mt<2; ++mt){
      const int row = wm*32 + mt*16 + lr;
      const int kb = (lg*16) ^ ((((row>>1)&3))<<4);
      af[mt] = *(const short8*)((const char*)Al[buf] + row*64 + kb);
    }
    #pragma unroll
    for (int p=0; p<2; ++p)
      #pragma unroll
      for (int nt=0; nt<4; ++nt){
        const int brow = p*128 + wn*64 + nt*16 + lr;
        const int kb = (lg*16) ^ ((((brow>>1)&3))<<4);
        bf[p][nt] = *(const short8*)((const char*)Bl[buf] + brow*64 + kb);
      }
    #pragma unroll
    for (int p=0; p<2; ++p)
      #pragma unroll
      for (int mt=0; mt<2; ++mt)
        #pragma unroll
        for (int nt=0; nt<4; ++nt)
          acc[p][mt][nt] = __builtin_amdgcn_mfma_f32_16x16x32_bf16(af[mt], bf[p][nt], acc[p][mt][nt], 0,0,0);
    __syncthreads();
  }

  float bcol[2][4], gcol[2][4], becol[2][4];
  #pragma unroll
  for (int p=0;p<2;++p)
    #pragma unroll
    for (int nt=0;nt<4;++nt){
      const int col = p*128 + wn*64 + nt*16 + lr;
      bcol[p][nt] = bias[col]; gcol[p][nt] = g[col]; becol[p][nt] = be[col];
    }
  float s8[2][4], q8[2][4];
  #pragma unroll
  for (int mt=0;mt<2;++mt)
    #pragma unroll
    for (int rr=0;rr<4;++rr){ s8[mt][rr]=0.f; q8[mt][rr]=0.f; }

  #pragma unroll
  for (int p=0;p<2;++p)
    #pragma unroll
    for (int mt=0;mt<2;++mt)
      #pragma unroll
      for (int nt=0;nt<4;++nt)
        #pragma unroll
        for (int rr=0;rr<4;++rr){
          const int row = m0 + wm*32 + mt*16 + lg*4 + rr;
          const int col = p*128 + wn*64 + nt*16 + lr;
          float val = acc[p][mt][nt][rr] + bcol[p][nt] + bf2f(x[(size_t)row*256 + col]);
          x[(size_t)row*256 + col] = f2bf(val);
          val = bf2f(f2bf(val));     // keep stats consistent with stored bf16
          acc[p][mt][nt][rr] = val;
          s8[mt][rr] += val; q8[mt][rr] += val*val;
        }
  #pragma unroll
  for (int mt=0;mt<2;++mt)
    #pragma unroll
    for (int rr=0;rr<4;++rr){
      #pragma unroll
      for (int m=1; m<16; m<<=1){
        s8[mt][rr] += __shfl_xor(s8[mt][rr], m);
        q8[mt][rr] += __shfl_xor(q8[mt][rr], m);
      }
      if (lr == 0){
        const int lrow = wm*32 + mt*16 + lg*4 + rr;
        sS[lrow][wn] = s8[mt][rr]; sQ[lrow][wn] = q8[mt][rr];
      }
    }
  __syncthreads();

  #pragma unroll
  for (int mt=0;mt<2;++mt)
    #pragma unroll
    for (int rr=0;rr<4;++rr){
      const int lrow = wm*32 + mt*16 + lg*4 + rr;
      const float mu = (sS[lrow][0] + sS[lrow][1]) * (1.f/256.f);
      const float var = (sQ[lrow][0] + sQ[lrow][1]) * (1.f/256.f) - mu*mu;
      const float rstd = rsqrtf(var + 1e-5f);
      #pragma unroll
      for (int p=0;p<2;++p)
        #pragma unroll
        for (int nt=0;nt<4;++nt){
          const int col = p*128 + wn*64 + nt*16 + lr;
          const float out = (acc[p][mt][nt][rr] - mu)*rstd*gcol[p][nt] + becol[p][nt];
          hb[(size_t)(m0+lrow)*256 + col] = f2bf(out);
        }
    }
}

// ---------------------------------------------------------------------------
// Fused causal attention, one block per (b,h): 8 waves x 512 threads.
// SWAPPED QK^T (S^T tile, q = lane column) => in-lane softmax.
// V transposed on-the-fly during staging. LDS 80 KiB -> 2 blocks/CU.
// ---------------------------------------------------------------------------
__global__ __launch_bounds__(512, 4)
void attn_kernel(const u16* __restrict__ qkv, u16* __restrict__ att)
{
  __shared__ __align__(16) u16 sK[16384];   // [256 t][64 d] swz (row 128B)
  __shared__ __align__(16) u16 sV[16384];   // [64 hd][256 t] swz (row 512B)
  __shared__ __align__(16) u16 sP[8192];    // 8 waves x [16 q][64 t] swz (row 128B)
  const int bh = blockIdx.x;
  const int b = bh >> 2, h = bh & 3;
  const int tid = threadIdx.x;
  const int w = tid >> 6, l = tid & 63, lr = l & 15, lg = l >> 4;
  const u16* base = qkv + (size_t)(b*256)*768;

  #pragma unroll
  for (int it=0; it<4; ++it){
    const int c = tid + it*512;
    const int t = c >> 3, p = c & 7;
    uint4 val = *(const uint4*)(base + (size_t)t*768 + 256 + h*64 + p*8);
    *(uint4*)((char*)sK + t*128 + ((p*16) ^ ((t&7)<<4))) = val;
  }
  #pragma unroll
  for (int it=0; it<8; ++it){
    const int c = tid + it*512;
    const int t = c >> 4, hdq = c & 15;
    ushort4 v = *(const ushort4*)(base + (size_t)t*768 + 512 + h*64 + hdq*4);
    #pragma unroll
    for (int j=0;j<4;++j){
      const int hd = hdq*4 + j;
      *(u16*)((char*)sV + hd*512 + ((t*2) ^ ((hd&31)<<4))) = ((const u16*)&v)[j];
    }
  }
  __syncthreads();

  char* sPw = (char*)sP + w*2048;
  const int swzq = (lr & 7) << 4;
  u16* ab = att + (size_t)(b*256)*256 + h*64;
  const float c1 = 0.09016844005556021f;   // (1/16) * log2(e)

  #pragma unroll
  for (int ph=0; ph<2; ++ph){
    const int rt = ph ? (15 - w) : w;
    const u16* qp = base + (size_t)(rt*16 + lr)*768 + h*64;
    const short8 qf0 = *(const short8*)(qp + lg*8);
    const short8 qf1 = *(const short8*)(qp + 32 + lg*8);

    f32x4 acc[16];
    #pragma unroll
    for (int nt=0; nt<16; ++nt) acc[nt] = (f32x4){0.f,0.f,0.f,0.f};
    #pragma unroll
    for (int nt=0; nt<16; ++nt){
      if (nt <= rt){
        const int row = nt*16 + lr;
        const int swz = (row & 7) << 4;
        short8 k0 = *(const short8*)((const char*)sK + row*128 + ((lg*16) ^ swz));
        short8 k1 = *(const short8*)((const char*)sK + row*128 + ((64 + lg*16) ^ swz));
        acc[nt] = __builtin_amdgcn_mfma_f32_16x16x32_bf16(k0, qf0, acc[nt], 0,0,0);
        acc[nt] = __builtin_amdgcn_mfma_f32_16x16x32_bf16(k1, qf1, acc[nt], 0,0,0);
      }
    }
    #pragma unroll
    for (int nt=0; nt<16; ++nt){
      if (nt == rt){
        #pragma unroll
        for (int r=0;r<4;++r)
          acc[nt][r] = (lg*4 + r > lr) ? -3.0e38f : acc[nt][r];
      }
    }

    float m_ = -3.0e38f;
    #pragma unroll
    for (int nt=0; nt<16; ++nt){
      if (nt <= rt){
        float t01 = fmaxf(acc[nt][0], acc[nt][1]);
        float t23 = fmaxf(acc[nt][2], acc[nt][3]);
        m_ = fmaxf(m_, fmaxf(t01, t23));
      }
    }
    m_ = fmaxf(m_, __shfl_xor(m_, 16));
    m_ = fmaxf(m_, __shfl_xor(m_, 32));
    const float mm = m_ * c1;
    float s_ = 0.f;
    #pragma unroll
    for (int nt=0; nt<16; ++nt){
      if (nt <= rt){
        #pragma unroll
        for (int r=0;r<4;++r){
          const float p = exp2f(fmaf(acc[nt][r], c1, -mm));
          acc[nt][r] = p;
          s_ += p;
        }
      }
    }
    s_ += __shfl_xor(s_, 16);
    s_ += __shfl_xor(s_, 32);
    const float inv = 1.f / s_;

    f32x4 oacc[4];
    #pragma unroll
    for (int nt=0; nt<4; ++nt) oacc[nt] = (f32x4){0.f,0.f,0.f,0.f};
    #pragma unroll
    for (int c=0; c<4; ++c){
      if (c <= (rt >> 2)){
        #pragma unroll
        for (int e=0; e<4; ++e){
          const int nt = 4*c + e;
          ushort4 pk;
          #pragma unroll
          for (int r=0;r<4;++r){
            const float val = (nt <= rt) ? acc[nt][r] * inv : 0.f;
            ((u16*)&pk)[r] = f2bf(val);
          }
          *(ushort4*)(sPw + lr*128 + ((e*32 + lg*8) ^ swzq)) = pk;
        }
        #pragma unroll
        for (int kc=0; kc<2; ++kc){
          const int tc = 2*c + kc;
          if (tc <= (rt >> 1)){
            const short8 ap = *(const short8*)(sPw + lr*128 + ((kc*64 + lg*16) ^ swzq));
            #pragma unroll
            for (int nt=0; nt<4; ++nt){
              const int vrow = nt*16 + lr;
              const short8 bv = *(const short8*)((const char*)sV + vrow*512 +
                                   ((tc*64 + lg*16) ^ ((vrow&31)<<4)));
              oacc[nt] = __builtin_amdgcn_mfma_f32_16x16x32_bf16(ap, bv, oacc[nt], 0,0,0);
            }
          }
        }
      }
    }

    #pragma unroll
    for (int nt=0; nt<4; ++nt)
      #pragma unroll
      for (int r=0;r<4;++r){
        const int row = rt*16 + lg*4 + r;
        ab[(size_t)row*256 + nt*16 + lr] = f2bf(oacc[nt][r]);
      }
  }
}

// ---------------------------------------------------------------------------
extern "C" void kernel_launch(void* const* d_in, const int* in_sizes, int n_in,
                              void* d_out, int out_size, void* d_ws, size_t ws_size,
                              hipStream_t stream)
{
  (void)in_sizes; (void)n_in; (void)out_size; (void)ws_size;
  const int*   idx = (const int*)  d_in[0];
  const float* tok = (const float*)d_in[1];
  const float* Wq  = (const float*)d_in[2];
  const float* Wk  = (const float*)d_in[3];
  const float* Wv  = (const float*)d_in[4];
  const float* Wo  = (const float*)d_in[5];
  const float* bo  = (const float*)d_in[6];
  const float* W1  = (const float*)d_in[7];
  const float* b1  = (const float*)d_in[8];
  const float* W2  = (const float*)d_in[9];
  const float* b2  = (const float*)d_in[10];
  const float* g1  = (const float*)d_in[11];
  const float* be1 = (const float*)d_in[12];
  const float* g2  = (const float*)d_in[13];
  const float* be2 = (const float*)d_in[14];
  const float* gf  = (const float*)d_in[15];
  const float* bfi = (const float*)d_in[16];
  const float* Wh  = (const float*)d_in[17];
  const float* bh  = (const float*)d_in[18];

  char* ws = (char*)d_ws;
  u16*   x    = (u16*)ws;    ws += (size_t)32768*256*2;   // residual stream bf16
  u16*   hb   = (u16*)ws;    ws += (size_t)32768*256*2;   // LN output bf16
  u16*   mid  = (u16*)ws;    ws += (size_t)32768*256*2;   // FFN mid bf16
  u16*   qkv  = (u16*)ws;    ws += (size_t)32768*768*2;
  u16*   att  = (u16*)ws;    ws += (size_t)32768*256*2;   // attn out bf16
  u16*   WqkvT= (u16*)ws;    ws += (size_t)8*768*256*2;
  u16*   WoT  = (u16*)ws;    ws += (size_t)8*256*256*2;
  u16*   W1T  = (u16*)ws;    ws += (size_t)8*256*256*2;
  u16*   W2T  = (u16*)ws;    ws += (size_t)8*256*256*2;
  u16*   WhT  = (u16*)ws;    ws += (size_t)512*256*2;

  wconv_kernel<<<dim3(32,49),512,0,stream>>>(Wq,Wk,Wv,Wo,W1,W2,Wh,WqkvT,WoT,W1T,W2T,WhT);
  embed_ln_kernel<<<8192,256,0,stream>>>(idx, tok, g1, be1, x, hb);
  for (int l=0; l<8; ++l){
    gemm_kernel<true,false,false><<<dim3(256,6),256,0,stream>>>(
        hb, WqkvT + (size_t)l*196608, nullptr, qkv, 768);
    attn_kernel<<<512,512,0,stream>>>(qkv, att);
    gemm_res_ln_kernel<<<512,256,0,stream>>>(
        att, WoT + (size_t)l*65536, bo + l*256, g2 + l*256, be2 + l*256, x, hb);
    gemm_kernel<true,true,true><<<dim3(256,2),256,0,stream>>>(
        hb, W1T + (size_t)l*65536, b1 + l*256, mid, 256);
    const float* gn = (l < 7) ? (g1 + (l+1)*256) : gf;
    const float* bn = (l < 7) ? (be1 + (l+1)*256) : bfi;
    gemm_res_ln_kernel<<<512,256,0,stream>>>(
        mid, W2T + (size_t)l*65536, b2 + l*256, gn, bn, x, hb);
  }
  gemm_kernel<false,false,true><<<dim3(256,4),256,0,stream>>>(
      hb, WhT, bh, (float*)d_out, 512);
}